// Round 3
// baseline (191.178 us; speedup 1.0000x reference)
//
#include <hip/hip_runtime.h>
#include <hip/hip_bf16.h>

// LightningAttention MI355X — round 11.
// R10 + k_qkv occupancy restructure: 64-row/512-thr blocks -> 32-row/512-thr blocks
//   (grid 2048). Wave = 1 head x 32 rows. acc 48->24 AGPR, A-frags 32->16 VGPR,
//   weight double-buffer dropped (-24 VGPR; TLP replaces ILP), LDS 39424->19712B.
//   Goal: cross the wave/SIMD register threshold (latency-bound kernel, 7x stall
//   factor, OccupancyPercent ~19%).
// k_prep / k_mprep / k_zout unchanged from R10.
// B=8 T=8192 DM=128 H=8 Dh=16. Split-bf16 (hi+lo) on all MFMA surfaces except q' (bf16).

typedef __attribute__((ext_vector_type(8))) short short8;   // 8 bf16 (MFMA A/B frag)
typedef __attribute__((ext_vector_type(4))) float floatx4;  // MFMA C/D frag

#define DEV __device__ __forceinline__
#define MFMA __builtin_amdgcn_mfma_f32_16x16x32_bf16

#define XPAD 136   // x-tile row stride in shorts (17x16B slots, odd multiple -> conflict-free)

DEV unsigned short bfh(float f) {
  unsigned int x = __float_as_uint(f);
  x += 0x7fffu + ((x >> 16) & 1u);     // RNE
  return (unsigned short)(x >> 16);
}
DEV float bfdec(unsigned short u) { return __uint_as_float(((unsigned int)u) << 16); }
DEV void splitf(float f, unsigned short& h, unsigned short& l) {
  h = bfh(f);
  l = bfh(f - bfdec(h));
}
DEV void split8(const float* p, short8& h8, short8& l8) {
  float4 a = *(const float4*)p;
  float4 b = *(const float4*)(p + 4);
  float v[8] = {a.x, a.y, a.z, a.w, b.x, b.y, b.z, b.w};
  union { short8 s; unsigned short u[8]; } H, L;
#pragma unroll
  for (int i = 0; i < 8; ++i) splitf(v[i], H.u[i], L.u[i]);
  h8 = H.s; l8 = L.s;
}

// Register transpose (verified R5-R7): C-layout tile val(n=lane16, m=mt*16+quad*4+r),
// rows m0/m1 -> split frag F[lane16][k=quad*8+j] over the 32-wide m-window.
DEV void xpose_frag(floatx4 m0, floatx4 m1, int lane16, int quad,
                    short8& hi, short8& lo) {
  union { short8 s; unsigned short u[8]; } H, L;
#pragma unroll
  for (int j = 0; j < 8; ++j) {
    int srcLane = lane16 + (((quad & 1) * 2 + (j >> 2)) << 4);
    float vA = __shfl(m0[j & 3], srcLane, 64);
    float vB = __shfl(m1[j & 3], srcLane, 64);
    float v = (quad < 2) ? vA : vB;
    splitf(v, H.u[j], L.u[j]);
  }
  hi = H.s; lo = L.s;
}

// ---------------- k_prep: Wq/Wk/Wv split-transpose + zero ctx/ksum ----------------
__global__ void k_prep(const float* __restrict__ Wq, const float* __restrict__ Wk,
                       const float* __restrict__ Wv,
                       unsigned short* __restrict__ WTh, unsigned short* __restrict__ WTl,
                       float* __restrict__ ctxz) {
  int gid = blockIdx.x * 256 + threadIdx.x;
  if (gid < 6144) {               // 3 mats x 128 n x 16 k-groups of 8
    int mat = gid >> 11, r = gid & 2047, n = r >> 4, k0 = (r & 15) * 8;
    const float* W = (mat == 0) ? Wq : (mat == 1) ? Wk : Wv;
    union { uint4 q; unsigned short u[8]; } oh, ol;
#pragma unroll
    for (int i = 0; i < 8; ++i) splitf(W[(size_t)(k0 + i) * 128 + n], oh.u[i], ol.u[i]);
    *(uint4*)&WTh[mat * 16384 + n * 128 + k0] = oh.q;
    *(uint4*)&WTl[mat * 16384 + n * 128 + k0] = ol.q;
  } else if (gid < 6144 + 17408) {
    ctxz[gid - 6144] = 0.0f;      // ctx (16384) + ksum (1024)
  }
}

// ---------------- kernel 1: qkv GEMM + rope/elu + q'/ksum/ctx ----------------
// 2048 blocks x 512 thr; block = 32 rows; wave w = head w over those 32 rows.
__global__ __launch_bounds__(512) void k_qkv(
    const float* __restrict__ x,
    const unsigned short* __restrict__ WTh, const unsigned short* __restrict__ WTl,
    const float* __restrict__ bq, const float* __restrict__ bk, const float* __restrict__ bv,
    float* __restrict__ ctx, float* __restrict__ ksum,
    unsigned short* __restrict__ qws) {
  __shared__ unsigned short xh[32 * XPAD], xl[32 * XPAD];   // pre-split x tile [row][k]
  __shared__ float rc[32][9], rs[32][9];
  const int tid = threadIdx.x;
  const int row0 = blockIdx.x * 32;
  const int b = row0 >> 13;
  const int t0 = row0 & 8191;

  if (tid < 256) {  // rope table: 256 threads -> 32 rows x 8 j
    int r = tid >> 3, j = tid & 7;
    float invf = 1.0f / powf(10000.0f, (float)j * 0.125f);
    float s, c;
    sincosf((float)(t0 + r) * invf, &s, &c);
    rc[r][j] = c; rs[r][j] = s;
  }
  {  // stage x, split ONCE per element: 512 thr -> 32 rows x 16 col-groups of 8
    int r = tid >> 4, cg = (tid & 15) * 8;
    const float* xp = x + (size_t)(row0 + r) * 128 + cg;
    short8 h0, l0;
    split8(xp, h0, l0);
    *(short8*)&xh[r * XPAD + cg] = h0;
    *(short8*)&xl[r * XPAD + cg] = l0;
  }
  __syncthreads();                 // only barrier

  const int l = tid & 63, w = tid >> 6;       // wave w owns head w
  const int lane16 = l & 15, quad = l >> 4;

  floatx4 acc[3][2];               // [mat: q,k,v][mt]  = 24 AGPRs
#pragma unroll
  for (int i = 0; i < 3; ++i)
#pragma unroll
    for (int j = 0; j < 2; ++j) acc[i][j] = (floatx4){0.f, 0.f, 0.f, 0.f};

  // weight base offsets per mat (ks advances by +32 shorts)
  size_t wbase[3];
#pragma unroll
  for (int mat = 0; mat < 3; ++mat)
    wbase[mat] = (size_t)mat * 16384 + (size_t)(w * 16 + lane16) * 128 + quad * 8;

#pragma unroll
  for (int ks = 0; ks < 4; ++ks) {
    short8 wh[3], wl[3];           // single-buffered weight frags (TLP hides L2 latency)
#pragma unroll
    for (int mat = 0; mat < 3; ++mat) {
      wh[mat] = *(const short8*)(WTh + wbase[mat] + ks * 32);
      wl[mat] = *(const short8*)(WTl + wbase[mat] + ks * 32);
    }
    short8 afh[2], afl[2];
#pragma unroll
    for (int mt = 0; mt < 2; ++mt) {
      int off = (mt * 16 + lane16) * XPAD + ks * 32 + quad * 8;
      afh[mt] = *(const short8*)&xh[off];
      afl[mt] = *(const short8*)&xl[off];
    }
#pragma unroll
    for (int mat = 0; mat < 3; ++mat) {
#pragma unroll
      for (int mt = 0; mt < 2; ++mt) {
        acc[mat][mt] = MFMA(afh[mt], wh[mat], acc[mat][mt], 0, 0, 0);
        acc[mat][mt] = MFMA(afl[mt], wh[mat], acc[mat][mt], 0, 0, 0);
        acc[mat][mt] = MFMA(afh[mt], wl[mat], acc[mat][mt], 0, 0, 0);
      }
    }
  }

  // bias (lane16 = col within head)
  {
    int col = w * 16 + lane16;
    float bias[3] = {bq[col], bk[col], bv[col]};
#pragma unroll
    for (int mat = 0; mat < 3; ++mat)
#pragma unroll
      for (int mt = 0; mt < 2; ++mt)
#pragma unroll
        for (int r = 0; r < 4; ++r) acc[mat][mt][r] += bias[mat];
  }

  // rope + elu+1 on q (mat 0) and k (mat 1). lane16 = d; t = mt*16 + quad*4 + r.
  {
    const int d = lane16, j = d & 7;
#pragma unroll
    for (int mt = 0; mt < 2; ++mt) {
      float cc[4], ss[4];
#pragma unroll
      for (int r = 0; r < 4; ++r) {
        int tl = mt * 16 + quad * 4 + r;
        cc[r] = rc[tl][j]; ss[r] = rs[tl][j];
      }
#pragma unroll
      for (int mat = 0; mat < 2; ++mat) {
#pragma unroll
        for (int r = 0; r < 4; ++r) {
          float v = acc[mat][mt][r];
          float p = __shfl_xor(v, 8);          // pair (d, d+8)
          float nv = (d < 8) ? (v * cc[r] - p * ss[r]) : (p * ss[r] + v * cc[r]);
          acc[mat][mt][r] = (nv > 0.f) ? (nv + 1.f) : __expf(nv);
        }
      }
    }
  }

  // ksum[h=w][d] from k
  {
    float s = 0.f;
#pragma unroll
    for (int mt = 0; mt < 2; ++mt)
#pragma unroll
      for (int r = 0; r < 4; ++r) s += acc[1][mt][r];
    s += __shfl_xor(s, 16);
    s += __shfl_xor(s, 32);
    if (l < 16) atomicAdd(&ksum[(b * 8 + w) * 16 + lane16], s);
  }

  // q' -> ws bf16 [t][128]
#pragma unroll
  for (int mt = 0; mt < 2; ++mt)
#pragma unroll
    for (int r = 0; r < 4; ++r)
      qws[(size_t)(row0 + mt * 16 + quad * 4 + r) * 128 + w * 16 + lane16] =
          bfh(acc[0][mt][r]);

  // ctx[h=w] += K^T V via register transpose (one 32-row t-window)
  {
    floatx4 c = (floatx4){0.f, 0.f, 0.f, 0.f};
    short8 kh, kl, vh, vl;
    xpose_frag(acc[1][0], acc[1][1], lane16, quad, kh, kl);
    xpose_frag(acc[2][0], acc[2][1], lane16, quad, vh, vl);
    c = MFMA(kh, vh, c, 0, 0, 0);
    c = MFMA(kl, vh, c, 0, 0, 0);
    c = MFMA(kh, vl, c, 0, 0, 0);
#pragma unroll
    for (int r = 0; r < 4; ++r)
      atomicAdd(&ctx[((size_t)(b * 8 + w) * 16 + quad * 4 + r) * 16 + lane16], c[r]);
  }
}

// ---------------- k_mprep: M = C_h @ Wo_h (fp32) -> frag-major permuted split-bf16 ----------------
// Consumer frag (nt,ks), lane l reads 16B at group ((nt*4+ks)*64 + l); element j = qc ks*32+(l>>4)*8+j.
__global__ void k_mprep(const float* __restrict__ Wo, const float* __restrict__ ctx,
                        unsigned short* __restrict__ MTh, unsigned short* __restrict__ MTl) {
  int gid = blockIdx.x * 256 + threadIdx.x;   // 64 blocks: 8 b x 128 oc x 16 qc-groups
  int b = gid >> 11, r = gid & 2047, oc = r >> 4, qcg = r & 15;
  int h = qcg >> 1, d0 = (qcg & 1) * 8;
  const float* C = ctx + (size_t)(b * 8 + h) * 256;   // [d][e]
  float m[8] = {0.f, 0.f, 0.f, 0.f, 0.f, 0.f, 0.f, 0.f};
#pragma unroll 4
  for (int e = 0; e < 16; ++e) {
    float wv = Wo[(size_t)(h * 16 + e) * 128 + oc];
#pragma unroll
    for (int i = 0; i < 8; ++i) m[i] += C[(d0 + i) * 16 + e] * wv;
  }
  union { uint4 q; unsigned short u[8]; } oh, ol;
#pragma unroll
  for (int i = 0; i < 8; ++i) splitf(m[i], oh.u[i], ol.u[i]);
  // permuted group index: nt=oc>>4, ks=qcg>>2, l = (qcg&3)*16 + (oc&15)
  int grp = (((oc >> 4) * 4 + (qcg >> 2)) * 64) + (qcg & 3) * 16 + (oc & 15);
  *(uint4*)&MTh[(size_t)b * 16384 + grp * 8] = oh.q;
  *(uint4*)&MTl[(size_t)b * 16384 + grp * 8] = ol.q;
}

// ---------------- kernel 2: out = (z .* q') @ M + bo. M read direct from L2. ----------------
// 1024 blocks x 256 thr; wave w owns rows [row0 + w*16, +16). M frags (1KB coalesced per
// load) come straight from global — M is 64KB/batch, guaranteed L2-resident; LDS staging
// capped occupancy at 2 blocks/CU and serialized behind a 64KB barrier.
__global__ __launch_bounds__(256) void k_zout(
    const unsigned short* __restrict__ qws,
    const unsigned short* __restrict__ MTh, const unsigned short* __restrict__ MTl,
    const float* __restrict__ bo, const float* __restrict__ ksum,
    float* __restrict__ out) {
  __shared__ float ksumS[128], boS[128];
  const int tid = threadIdx.x;
  const int row0 = blockIdx.x * 64;
  const int b = row0 >> 13;
  const int l = tid & 63, w = tid >> 6;
  const int lane16 = l & 15, quad = l >> 4;

  if (tid < 128) ksumS[tid] = ksum[b * 128 + tid];
  else boS[tid - 128] = bo[tid - 128];
  __syncthreads();

  // A-frags: q' direct from ws (already frag-layout), z in-reg, scale+split
  short8 ah[4], al[4];
  {
    int trow = row0 + w * 16 + lane16;      // lane16 = t within the wave's 16-row strip
#pragma unroll
    for (int ks = 0; ks < 4; ++ks) {
      union { short8 s8; unsigned short u[8]; } qq;
      qq.s8 = *(const short8*)&qws[(size_t)trow * 128 + ks * 32 + quad * 8];
      int kb = ks * 32 + quad * 8;
      float s = 0.f;
#pragma unroll
      for (int j = 0; j < 8; ++j) s += bfdec(qq.u[j]) * ksumS[kb + j];
      s += __shfl_xor(s, 16);        // combine the two 8-halves of the head
      float z = 1.0f / (s + 1e-6f);
      union { short8 s8; unsigned short u[8]; } H, L;
#pragma unroll
      for (int j = 0; j < 8; ++j) splitf(bfdec(qq.u[j]) * z, H.u[j], L.u[j]);
      ah[ks] = H.s8;
      al[ks] = L.s8;
    }
  }

  floatx4 oacc[8];
#pragma unroll
  for (int i = 0; i < 8; ++i) oacc[i] = (floatx4){0.f, 0.f, 0.f, 0.f};

  const short8* gH = (const short8*)(MTh + (size_t)b * 16384) + l;
  const short8* gL = (const short8*)(MTl + (size_t)b * 16384) + l;

  // ks-major frag order (consecutive iterations hit different accumulators);
  // memory group index g = nt*4 + ks. Depth-2 prefetch ring in named registers
  // (fully unrolled -> all indices static, no scratch).
  short8 h0 = gH[0 * 64], L0 = gL[0 * 64];       // f=0: nt=0 ks=0 -> g=0
  short8 h1 = gH[4 * 64], L1 = gL[4 * 64];       // f=1: nt=1 ks=0 -> g=4
#pragma unroll
  for (int f = 0; f < 32; ++f) {
    short8 ch = (f & 1) ? h1 : h0;
    short8 cl = (f & 1) ? L1 : L0;
    if (f + 2 < 32) {
      int f2 = f + 2;
      int g2 = (f2 & 7) * 4 + (f2 >> 3);         // nt=f2&7, ks=f2>>3
      if (f & 1) { h1 = gH[g2 * 64]; L1 = gL[g2 * 64]; }
      else       { h0 = gH[g2 * 64]; L0 = gL[g2 * 64]; }
    }
    int nt = f & 7, ks = f >> 3;
    oacc[nt] = MFMA(ah[ks], ch, oacc[nt], 0, 0, 0);
    oacc[nt] = MFMA(al[ks], ch, oacc[nt], 0, 0, 0);
    oacc[nt] = MFMA(ah[ks], cl, oacc[nt], 0, 0, 0);
  }

#pragma unroll
  for (int nt = 0; nt < 8; ++nt) {
    int oc = nt * 16 + lane16;
    float bb = boS[oc];
#pragma unroll
    for (int r = 0; r < 4; ++r) {
      int t = row0 + w * 16 + quad * 4 + r;
      out[(size_t)t * 128 + oc] = oacc[nt][r] + bb;
    }
  }
}

extern "C" void kernel_launch(void* const* d_in, const int* in_sizes, int n_in,
                              void* d_out, int out_size, void* d_ws, size_t ws_size,
                              hipStream_t stream) {
  const float* x  = (const float*)d_in[0];
  const float* Wq = (const float*)d_in[1];
  const float* bq = (const float*)d_in[2];
  const float* Wk = (const float*)d_in[3];
  const float* bk = (const float*)d_in[4];
  const float* Wv = (const float*)d_in[5];
  const float* bv = (const float*)d_in[6];
  const float* Wo = (const float*)d_in[7];
  const float* bo = (const float*)d_in[8];
  float* out = (float*)d_out;

  // ws: qws 16.78MB | WTh 96KB | WTl 96KB | ctx 64KB | ksum 4KB | MTh 256KB | MTl 256KB
  unsigned short* qws = (unsigned short*)d_ws;         // 65536*128 shorts
  unsigned short* WTh = qws + 8388608;                 // 3 x 16384
  unsigned short* WTl = WTh + 49152;
  float* ctx  = (float*)(WTl + 49152);                 // 16384 f
  float* ksum = ctx + 16384;                           // 1024 f
  unsigned short* MTh = (unsigned short*)(ksum + 1024);  // 8 x 16384
  unsigned short* MTl = MTh + 131072;

  k_prep<<<92, 256, 0, stream>>>(Wq, Wk, Wv, WTh, WTl, ctx);
  k_qkv<<<2048, 512, 0, stream>>>(x, WTh, WTl, bq, bk, bv, ctx, ksum, qws);
  k_mprep<<<64, 256, 0, stream>>>(Wo, ctx, MTh, MTl);
  k_zout<<<1024, 256, 0, stream>>>(qws, MTh, MTl, bo, ksum, out);
}

// Round 4
// 167.640 us; speedup vs baseline: 1.1404x; 1.1404x over previous
//
#include <hip/hip_runtime.h>
#include <hip/hip_bf16.h>

// LightningAttention MI355X — round 12.
// k_qkv reverted to R10's exact 64-row structure (best measured: 57.9us), EXCEPT:
//   ctx/ksum atomicAdd -> per-block partial STORES (8.7KB/block slot, no contention)
//   + new k_red reduction kernel (sums 128 partials per (b,h)).
// Theory: R10's 19% occupancy on a fully-resident 32-wave/CU grid = long atomic-drain
//   tail (2.1M RMW to 64KB ctx = ~4K serialized ops/cache-line). R11's A/B showed
//   stall time scales with atomic count (+8.7MB atomic writebacks -> +24us).
// k_mprep / k_zout unchanged. k_prep loses the ctx/ksum zeroing (k_red overwrites).
// B=8 T=8192 DM=128 H=8 Dh=16. Split-bf16 (hi+lo) on all MFMA surfaces except q' (bf16).

typedef __attribute__((ext_vector_type(8))) short short8;   // 8 bf16 (MFMA A/B frag)
typedef __attribute__((ext_vector_type(4))) float floatx4;  // MFMA C/D frag

#define DEV __device__ __forceinline__
#define MFMA __builtin_amdgcn_mfma_f32_16x16x32_bf16

#define XPAD 136   // x-tile row stride in shorts. 136 -> LDS 39424B -> 4 blocks/CU. Do not grow.

DEV unsigned short bfh(float f) {
  unsigned int x = __float_as_uint(f);
  x += 0x7fffu + ((x >> 16) & 1u);     // RNE
  return (unsigned short)(x >> 16);
}
DEV float bfdec(unsigned short u) { return __uint_as_float(((unsigned int)u) << 16); }
DEV void splitf(float f, unsigned short& h, unsigned short& l) {
  h = bfh(f);
  l = bfh(f - bfdec(h));
}
DEV void split8(const float* p, short8& h8, short8& l8) {
  float4 a = *(const float4*)p;
  float4 b = *(const float4*)(p + 4);
  float v[8] = {a.x, a.y, a.z, a.w, b.x, b.y, b.z, b.w};
  union { short8 s; unsigned short u[8]; } H, L;
#pragma unroll
  for (int i = 0; i < 8; ++i) splitf(v[i], H.u[i], L.u[i]);
  h8 = H.s; l8 = L.s;
}

// Register transpose (verified R5-R7): C-layout tile val(n=lane16, m=mt*16+quad*4+r),
// rows m0/m1 -> split frag F[lane16][k=quad*8+j] over the 32-wide m-window.
DEV void xpose_frag(floatx4 m0, floatx4 m1, int lane16, int quad,
                    short8& hi, short8& lo) {
  union { short8 s; unsigned short u[8]; } H, L;
#pragma unroll
  for (int j = 0; j < 8; ++j) {
    int srcLane = lane16 + (((quad & 1) * 2 + (j >> 2)) << 4);
    float vA = __shfl(m0[j & 3], srcLane, 64);
    float vB = __shfl(m1[j & 3], srcLane, 64);
    float v = (quad < 2) ? vA : vB;
    splitf(v, H.u[j], L.u[j]);
  }
  hi = H.s; lo = L.s;
}

// ---------------- k_prep: Wq/Wk/Wv split-transpose ----------------
__global__ void k_prep(const float* __restrict__ Wq, const float* __restrict__ Wk,
                       const float* __restrict__ Wv,
                       unsigned short* __restrict__ WTh, unsigned short* __restrict__ WTl) {
  int gid = blockIdx.x * 256 + threadIdx.x;   // 24 blocks x 256 = 6144 exactly
  int mat = gid >> 11, r = gid & 2047, n = r >> 4, k0 = (r & 15) * 8;
  const float* W = (mat == 0) ? Wq : (mat == 1) ? Wk : Wv;
  union { uint4 q; unsigned short u[8]; } oh, ol;
#pragma unroll
  for (int i = 0; i < 8; ++i) splitf(W[(size_t)(k0 + i) * 128 + n], oh.u[i], ol.u[i]);
  *(uint4*)&WTh[mat * 16384 + n * 128 + k0] = oh.q;
  *(uint4*)&WTl[mat * 16384 + n * 128 + k0] = ol.q;
}

// ---------------- kernel 1: qkv GEMM + rope/elu + q'/ksum/ctx partials ----------------
// 1024 blocks x 512 thr; block = 64 rows; wave w = head w.
__global__ __launch_bounds__(512) void k_qkv(
    const float* __restrict__ x,
    const unsigned short* __restrict__ WTh, const unsigned short* __restrict__ WTl,
    const float* __restrict__ bq, const float* __restrict__ bk, const float* __restrict__ bv,
    float* __restrict__ P,            // partials: [1024 blk][8 h][272] (256 ctx + 16 ksum)
    unsigned short* __restrict__ qws) {
  __shared__ unsigned short xh[64 * XPAD], xl[64 * XPAD];   // pre-split x tile [row][k]
  __shared__ float rc[64][9], rs[64][9];
  const int tid = threadIdx.x;
  const int row0 = blockIdx.x * 64;
  const int t0 = row0 & 8191;

  {  // rope table: 512 threads -> 64 rows x 8 j
    int r = tid >> 3, j = tid & 7;
    float invf = 1.0f / powf(10000.0f, (float)j * 0.125f);
    float s, c;
    sincosf((float)(t0 + r) * invf, &s, &c);
    rc[r][j] = c; rs[r][j] = s;
  }
  {  // stage x, split ONCE per element
    int r = tid >> 3, cg = (tid & 7) * 16;
    const float* xp = x + (size_t)(row0 + r) * 128 + cg;
    short8 h0, l0, h1, l1;
    split8(xp, h0, l0);
    split8(xp + 8, h1, l1);
    *(short8*)&xh[r * XPAD + cg] = h0;
    *(short8*)&xh[r * XPAD + cg + 8] = h1;
    *(short8*)&xl[r * XPAD + cg] = l0;
    *(short8*)&xl[r * XPAD + cg + 8] = l1;
  }
  __syncthreads();                 // only barrier

  const int l = tid & 63, w = tid >> 6;       // wave w owns head w
  const int lane16 = l & 15, quad = l >> 4;

  floatx4 acc[3][4];               // [mat: q,k,v][mt]  = 48 AGPRs
#pragma unroll
  for (int i = 0; i < 3; ++i)
#pragma unroll
    for (int j = 0; j < 4; ++j) acc[i][j] = (floatx4){0.f, 0.f, 0.f, 0.f};

  // weight base offsets per mat (ks advances by +32 shorts)
  size_t wbase[3];
#pragma unroll
  for (int mat = 0; mat < 3; ++mat)
    wbase[mat] = (size_t)mat * 16384 + (size_t)(w * 16 + lane16) * 128 + quad * 8;

  // double-buffered weight frags: prefetch ks+1 while computing ks
  short8 wh[2][3], wl[2][3];
#pragma unroll
  for (int mat = 0; mat < 3; ++mat) {
    wh[0][mat] = *(const short8*)(WTh + wbase[mat]);
    wl[0][mat] = *(const short8*)(WTl + wbase[mat]);
  }

#pragma unroll
  for (int ks = 0; ks < 4; ++ks) {
    const int cur = ks & 1, nxt = cur ^ 1;
    if (ks < 3) {
#pragma unroll
      for (int mat = 0; mat < 3; ++mat) {
        wh[nxt][mat] = *(const short8*)(WTh + wbase[mat] + (ks + 1) * 32);
        wl[nxt][mat] = *(const short8*)(WTl + wbase[mat] + (ks + 1) * 32);
      }
    }
    short8 afh[4], afl[4];
#pragma unroll
    for (int mt = 0; mt < 4; ++mt) {
      int off = (mt * 16 + lane16) * XPAD + ks * 32 + quad * 8;
      afh[mt] = *(const short8*)&xh[off];
      afl[mt] = *(const short8*)&xl[off];
    }
#pragma unroll
    for (int mat = 0; mat < 3; ++mat) {
#pragma unroll
      for (int mt = 0; mt < 4; ++mt) {
        acc[mat][mt] = MFMA(afh[mt], wh[cur][mat], acc[mat][mt], 0, 0, 0);
        acc[mat][mt] = MFMA(afl[mt], wh[cur][mat], acc[mat][mt], 0, 0, 0);
        acc[mat][mt] = MFMA(afh[mt], wl[cur][mat], acc[mat][mt], 0, 0, 0);
      }
    }
  }

  // bias (lane16 = col within head)
  {
    int col = w * 16 + lane16;
    float bias[3] = {bq[col], bk[col], bv[col]};
#pragma unroll
    for (int mat = 0; mat < 3; ++mat)
#pragma unroll
      for (int mt = 0; mt < 4; ++mt)
#pragma unroll
        for (int r = 0; r < 4; ++r) acc[mat][mt][r] += bias[mat];
  }

  // rope + elu+1 on q (mat 0) and k (mat 1). lane16 = d; t = mt*16 + quad*4 + r.
  {
    const int d = lane16, j = d & 7;
#pragma unroll
    for (int mt = 0; mt < 4; ++mt) {
      float cc[4], ss[4];
#pragma unroll
      for (int r = 0; r < 4; ++r) {
        int tl = mt * 16 + quad * 4 + r;
        cc[r] = rc[tl][j]; ss[r] = rs[tl][j];
      }
#pragma unroll
      for (int mat = 0; mat < 2; ++mat) {
#pragma unroll
        for (int r = 0; r < 4; ++r) {
          float v = acc[mat][mt][r];
          float p = __shfl_xor(v, 8);          // pair (d, d+8)
          float nv = (d < 8) ? (v * cc[r] - p * ss[r]) : (p * ss[r] + v * cc[r]);
          acc[mat][mt][r] = (nv > 0.f) ? (nv + 1.f) : __expf(nv);
        }
      }
    }
  }

  float* Pw = P + ((size_t)blockIdx.x * 8 + w) * 272;   // this block+head's partial slot

  // ksum partial [h=w][d] from k (plain store, no atomic)
  {
    float s = 0.f;
#pragma unroll
    for (int mt = 0; mt < 4; ++mt)
#pragma unroll
      for (int r = 0; r < 4; ++r) s += acc[1][mt][r];
    s += __shfl_xor(s, 16);
    s += __shfl_xor(s, 32);
    if (l < 16) Pw[256 + lane16] = s;
  }

  // q' -> ws bf16 [t][128]
#pragma unroll
  for (int mt = 0; mt < 4; ++mt)
#pragma unroll
    for (int r = 0; r < 4; ++r)
      qws[(size_t)(row0 + mt * 16 + quad * 4 + r) * 128 + w * 16 + lane16] =
          bfh(acc[0][mt][r]);

  // ctx partial [h=w] = K^T V via register transposes (2 t-windows of 32); plain stores
  {
    floatx4 c = (floatx4){0.f, 0.f, 0.f, 0.f};
#pragma unroll
    for (int ks2 = 0; ks2 < 2; ++ks2) {
      short8 kh, kl, vh, vl;
      xpose_frag(acc[1][ks2 * 2], acc[1][ks2 * 2 + 1], lane16, quad, kh, kl);
      xpose_frag(acc[2][ks2 * 2], acc[2][ks2 * 2 + 1], lane16, quad, vh, vl);
      c = MFMA(kh, vh, c, 0, 0, 0);
      c = MFMA(kl, vh, c, 0, 0, 0);
      c = MFMA(kh, vl, c, 0, 0, 0);
    }
#pragma unroll
    for (int r = 0; r < 4; ++r)
      Pw[(quad * 4 + r) * 16 + lane16] = c[r];
  }
}

// ---------------- k_red: reduce 128 tile-partials per (b,h) -> ctx, ksum ----------------
// 68 blocks x 256 = 17408 threads = 8 b x 8 h x 272 elements. Coalesced: for fixed lb,
// consecutive threads read consecutive floats.
__global__ void k_red(const float* __restrict__ P,
                      float* __restrict__ ctx, float* __restrict__ ksum) {
  int gid = blockIdx.x * 256 + threadIdx.x;
  int b = gid / 2176, rem = gid - b * 2176;
  int w = rem / 272, i = rem - w * 272;
  const float* p = P + ((size_t)b * 128 * 8 + w) * 272 + i;
  float s = 0.f;
#pragma unroll 8
  for (int lb = 0; lb < 128; ++lb) s += p[(size_t)lb * 8 * 272];
  if (i < 256) ctx[(b * 8 + w) * 256 + i] = s;
  else         ksum[(b * 8 + w) * 16 + (i - 256)] = s;
}

// ---------------- k_mprep: M = C_h @ Wo_h (fp32) -> frag-major permuted split-bf16 ----------------
// Consumer frag (nt,ks), lane l reads 16B at group ((nt*4+ks)*64 + l); element j = qc ks*32+(l>>4)*8+j.
__global__ void k_mprep(const float* __restrict__ Wo, const float* __restrict__ ctx,
                        unsigned short* __restrict__ MTh, unsigned short* __restrict__ MTl) {
  int gid = blockIdx.x * 256 + threadIdx.x;   // 64 blocks: 8 b x 128 oc x 16 qc-groups
  int b = gid >> 11, r = gid & 2047, oc = r >> 4, qcg = r & 15;
  int h = qcg >> 1, d0 = (qcg & 1) * 8;
  const float* C = ctx + (size_t)(b * 8 + h) * 256;   // [d][e]
  float m[8] = {0.f, 0.f, 0.f, 0.f, 0.f, 0.f, 0.f, 0.f};
#pragma unroll 4
  for (int e = 0; e < 16; ++e) {
    float wv = Wo[(size_t)(h * 16 + e) * 128 + oc];
#pragma unroll
    for (int i = 0; i < 8; ++i) m[i] += C[(d0 + i) * 16 + e] * wv;
  }
  union { uint4 q; unsigned short u[8]; } oh, ol;
#pragma unroll
  for (int i = 0; i < 8; ++i) splitf(m[i], oh.u[i], ol.u[i]);
  // permuted group index: nt=oc>>4, ks=qcg>>2, l = (qcg&3)*16 + (oc&15)
  int grp = (((oc >> 4) * 4 + (qcg >> 2)) * 64) + (qcg & 3) * 16 + (oc & 15);
  *(uint4*)&MTh[(size_t)b * 16384 + grp * 8] = oh.q;
  *(uint4*)&MTl[(size_t)b * 16384 + grp * 8] = ol.q;
}

// ---------------- kernel 2: out = (z .* q') @ M + bo. M read direct from L2. ----------------
// 1024 blocks x 256 thr; wave w owns rows [row0 + w*16, +16). M frags (1KB coalesced per
// load) come straight from global — M is 64KB/batch, guaranteed L2-resident.
__global__ __launch_bounds__(256) void k_zout(
    const unsigned short* __restrict__ qws,
    const unsigned short* __restrict__ MTh, const unsigned short* __restrict__ MTl,
    const float* __restrict__ bo, const float* __restrict__ ksum,
    float* __restrict__ out) {
  __shared__ float ksumS[128], boS[128];
  const int tid = threadIdx.x;
  const int row0 = blockIdx.x * 64;
  const int b = row0 >> 13;
  const int l = tid & 63, w = tid >> 6;
  const int lane16 = l & 15, quad = l >> 4;

  if (tid < 128) ksumS[tid] = ksum[b * 128 + tid];
  else boS[tid - 128] = bo[tid - 128];
  __syncthreads();

  // A-frags: q' direct from ws (already frag-layout), z in-reg, scale+split
  short8 ah[4], al[4];
  {
    int trow = row0 + w * 16 + lane16;      // lane16 = t within the wave's 16-row strip
#pragma unroll
    for (int ks = 0; ks < 4; ++ks) {
      union { short8 s8; unsigned short u[8]; } qq;
      qq.s8 = *(const short8*)&qws[(size_t)trow * 128 + ks * 32 + quad * 8];
      int kb = ks * 32 + quad * 8;
      float s = 0.f;
#pragma unroll
      for (int j = 0; j < 8; ++j) s += bfdec(qq.u[j]) * ksumS[kb + j];
      s += __shfl_xor(s, 16);        // combine the two 8-halves of the head
      float z = 1.0f / (s + 1e-6f);
      union { short8 s8; unsigned short u[8]; } H, L;
#pragma unroll
      for (int j = 0; j < 8; ++j) splitf(bfdec(qq.u[j]) * z, H.u[j], L.u[j]);
      ah[ks] = H.s8;
      al[ks] = L.s8;
    }
  }

  floatx4 oacc[8];
#pragma unroll
  for (int i = 0; i < 8; ++i) oacc[i] = (floatx4){0.f, 0.f, 0.f, 0.f};

  const short8* gH = (const short8*)(MTh + (size_t)b * 16384) + l;
  const short8* gL = (const short8*)(MTl + (size_t)b * 16384) + l;

  // ks-major frag order (consecutive iterations hit different accumulators);
  // memory group index g = nt*4 + ks. Depth-2 prefetch ring in named registers
  // (fully unrolled -> all indices static, no scratch).
  short8 h0 = gH[0 * 64], L0 = gL[0 * 64];       // f=0: nt=0 ks=0 -> g=0
  short8 h1 = gH[4 * 64], L1 = gL[4 * 64];       // f=1: nt=1 ks=0 -> g=4
#pragma unroll
  for (int f = 0; f < 32; ++f) {
    short8 ch = (f & 1) ? h1 : h0;
    short8 cl = (f & 1) ? L1 : L0;
    if (f + 2 < 32) {
      int f2 = f + 2;
      int g2 = (f2 & 7) * 4 + (f2 >> 3);         // nt=f2&7, ks=f2>>3
      if (f & 1) { h1 = gH[g2 * 64]; L1 = gL[g2 * 64]; }
      else       { h0 = gH[g2 * 64]; L0 = gL[g2 * 64]; }
    }
    int nt = f & 7, ks = f >> 3;
    oacc[nt] = MFMA(ah[ks], ch, oacc[nt], 0, 0, 0);
    oacc[nt] = MFMA(al[ks], ch, oacc[nt], 0, 0, 0);
    oacc[nt] = MFMA(ah[ks], cl, oacc[nt], 0, 0, 0);
  }

#pragma unroll
  for (int nt = 0; nt < 8; ++nt) {
    int oc = nt * 16 + lane16;
    float bb = boS[oc];
#pragma unroll
    for (int r = 0; r < 4; ++r) {
      int t = row0 + w * 16 + quad * 4 + r;
      out[(size_t)t * 128 + oc] = oacc[nt][r] + bb;
    }
  }
}

extern "C" void kernel_launch(void* const* d_in, const int* in_sizes, int n_in,
                              void* d_out, int out_size, void* d_ws, size_t ws_size,
                              hipStream_t stream) {
  const float* x  = (const float*)d_in[0];
  const float* Wq = (const float*)d_in[1];
  const float* bq = (const float*)d_in[2];
  const float* Wk = (const float*)d_in[3];
  const float* bk = (const float*)d_in[4];
  const float* Wv = (const float*)d_in[5];
  const float* bv = (const float*)d_in[6];
  const float* Wo = (const float*)d_in[7];
  const float* bo = (const float*)d_in[8];
  float* out = (float*)d_out;

  // ws: qws 16.78MB | WTh 96KB | WTl 96KB | ctx 64KB | ksum 4KB | MTh 256KB | MTl 256KB
  //     | P 8.9MB (ctx/ksum partials)  => ~27.1MB total
  unsigned short* qws = (unsigned short*)d_ws;         // 65536*128 shorts
  unsigned short* WTh = qws + 8388608;                 // 3 x 16384
  unsigned short* WTl = WTh + 49152;
  float* ctx  = (float*)(WTl + 49152);                 // 16384 f
  float* ksum = ctx + 16384;                           // 1024 f
  unsigned short* MTh = (unsigned short*)(ksum + 1024);  // 8 x 16384
  unsigned short* MTl = MTh + 131072;
  float* P = (float*)(MTl + 131072);                   // 1024 x 8 x 272 f

  k_prep<<<24, 256, 0, stream>>>(Wq, Wk, Wv, WTh, WTl);
  k_qkv<<<1024, 512, 0, stream>>>(x, WTh, WTl, bq, bk, bv, P, qws);
  k_red<<<68, 256, 0, stream>>>(P, ctx, ksum);
  k_mprep<<<64, 256, 0, stream>>>(Wo, ctx, MTh, MTl);
  k_zout<<<1024, 256, 0, stream>>>(qws, MTh, MTl, bo, ksum, out);
}

// Round 5
// 160.544 us; speedup vs baseline: 1.1908x; 1.0442x over previous
//
#include <hip/hip_runtime.h>
#include <hip/hip_bf16.h>

// LightningAttention MI355X — round 13.
// Full revert to R8 (best measured total: 161.5us) — k_qkv with atomics (R11 occupancy
// probe and R12 atomic->store probe BOTH regressed; R10 structure is the local optimum),
// LDS-staged k_zout — EXCEPT one change:
//   k_zout: 256thr/4 waves -> 512thr/8 waves per 128-row block (wave = one 16-row tile).
//   Same 64KB M staging. LDS caps at 2 blocks/CU either way; this doubles waves/SIMD
//   (2 -> 4), halves per-wave register state (oacc 64->32) and staging prologue.
// B=8 T=8192 DM=128 H=8 Dh=16. Split-bf16 (hi+lo) on all MFMA surfaces except q' (bf16).

typedef __attribute__((ext_vector_type(8))) short short8;   // 8 bf16 (MFMA A/B frag)
typedef __attribute__((ext_vector_type(4))) float floatx4;  // MFMA C/D frag

#define DEV __device__ __forceinline__
#define MFMA __builtin_amdgcn_mfma_f32_16x16x32_bf16

#define XPAD 136   // x-tile row stride in shorts. 136 -> LDS 39424B -> 4 blocks/CU. Do not grow.

DEV unsigned short bfh(float f) {
  unsigned int x = __float_as_uint(f);
  x += 0x7fffu + ((x >> 16) & 1u);     // RNE
  return (unsigned short)(x >> 16);
}
DEV float bfdec(unsigned short u) { return __uint_as_float(((unsigned int)u) << 16); }
DEV void splitf(float f, unsigned short& h, unsigned short& l) {
  h = bfh(f);
  l = bfh(f - bfdec(h));
}
DEV void split8(const float* p, short8& h8, short8& l8) {
  float4 a = *(const float4*)p;
  float4 b = *(const float4*)(p + 4);
  float v[8] = {a.x, a.y, a.z, a.w, b.x, b.y, b.z, b.w};
  union { short8 s; unsigned short u[8]; } H, L;
#pragma unroll
  for (int i = 0; i < 8; ++i) splitf(v[i], H.u[i], L.u[i]);
  h8 = H.s; l8 = L.s;
}

// Register transpose (verified R5-R7): C-layout tile val(n=lane16, m=mt*16+quad*4+r),
// rows m0/m1 -> split frag F[lane16][k=quad*8+j] over the 32-wide m-window.
DEV void xpose_frag(floatx4 m0, floatx4 m1, int lane16, int quad,
                    short8& hi, short8& lo) {
  union { short8 s; unsigned short u[8]; } H, L;
#pragma unroll
  for (int j = 0; j < 8; ++j) {
    int srcLane = lane16 + (((quad & 1) * 2 + (j >> 2)) << 4);
    float vA = __shfl(m0[j & 3], srcLane, 64);
    float vB = __shfl(m1[j & 3], srcLane, 64);
    float v = (quad < 2) ? vA : vB;
    splitf(v, H.u[j], L.u[j]);
  }
  hi = H.s; lo = L.s;
}

// async 16B global->LDS (per-lane gsrc; LDS dest must be wave-uniform base + lane*16)
DEV void async16(const void* g, void* l) {
  __builtin_amdgcn_global_load_lds(
      (const __attribute__((address_space(1))) unsigned int*)g,
      (__attribute__((address_space(3))) unsigned int*)l, 16, 0, 0);
}

// ---------------- k_prep: Wq/Wk/Wv split-transpose + zero ctx/ksum ----------------
__global__ void k_prep(const float* __restrict__ Wq, const float* __restrict__ Wk,
                       const float* __restrict__ Wv,
                       unsigned short* __restrict__ WTh, unsigned short* __restrict__ WTl,
                       float* __restrict__ ctxz) {
  int gid = blockIdx.x * 256 + threadIdx.x;
  if (gid < 6144) {               // 3 mats x 128 n x 16 k-groups of 8
    int mat = gid >> 11, r = gid & 2047, n = r >> 4, k0 = (r & 15) * 8;
    const float* W = (mat == 0) ? Wq : (mat == 1) ? Wk : Wv;
    union { uint4 q; unsigned short u[8]; } oh, ol;
#pragma unroll
    for (int i = 0; i < 8; ++i) splitf(W[(size_t)(k0 + i) * 128 + n], oh.u[i], ol.u[i]);
    *(uint4*)&WTh[mat * 16384 + n * 128 + k0] = oh.q;
    *(uint4*)&WTl[mat * 16384 + n * 128 + k0] = ol.q;
  } else if (gid < 6144 + 17408) {
    ctxz[gid - 6144] = 0.0f;      // ctx (16384) + ksum (1024)
  }
}

// ---------------- kernel 1: qkv GEMM + rope/elu + q'/ksum/ctx. 512 thr, wave=1 head ----------------
__global__ __launch_bounds__(512) void k_qkv(
    const float* __restrict__ x,
    const unsigned short* __restrict__ WTh, const unsigned short* __restrict__ WTl,
    const float* __restrict__ bq, const float* __restrict__ bk, const float* __restrict__ bv,
    float* __restrict__ ctx, float* __restrict__ ksum,
    unsigned short* __restrict__ qws) {
  __shared__ unsigned short xh[64 * XPAD], xl[64 * XPAD];   // pre-split x tile [row][k]
  __shared__ float rc[64][9], rs[64][9];
  const int tid = threadIdx.x;
  const int row0 = blockIdx.x * 64;
  const int b = row0 >> 13;
  const int t0 = row0 & 8191;

  {  // rope table: 512 threads -> 64 rows x 8 j
    int r = tid >> 3, j = tid & 7;
    float invf = 1.0f / powf(10000.0f, (float)j * 0.125f);
    float s, c;
    sincosf((float)(t0 + r) * invf, &s, &c);
    rc[r][j] = c; rs[r][j] = s;
  }
  {  // stage x, split ONCE per element
    int r = tid >> 3, cg = (tid & 7) * 16;
    const float* xp = x + (size_t)(row0 + r) * 128 + cg;
    short8 h0, l0, h1, l1;
    split8(xp, h0, l0);
    split8(xp + 8, h1, l1);
    *(short8*)&xh[r * XPAD + cg] = h0;
    *(short8*)&xh[r * XPAD + cg + 8] = h1;
    *(short8*)&xl[r * XPAD + cg] = l0;
    *(short8*)&xl[r * XPAD + cg + 8] = l1;
  }
  __syncthreads();                 // only barrier

  const int l = tid & 63, w = tid >> 6;       // wave w owns head w
  const int lane16 = l & 15, quad = l >> 4;

  floatx4 acc[3][4];               // [mat: q,k,v][mt]  = 48 AGPRs
#pragma unroll
  for (int i = 0; i < 3; ++i)
#pragma unroll
    for (int j = 0; j < 4; ++j) acc[i][j] = (floatx4){0.f, 0.f, 0.f, 0.f};

  // weight base offsets per mat (ks advances by +32 shorts)
  size_t wbase[3];
#pragma unroll
  for (int mat = 0; mat < 3; ++mat)
    wbase[mat] = (size_t)mat * 16384 + (size_t)(w * 16 + lane16) * 128 + quad * 8;

  // double-buffered weight frags: prefetch ks+1 while computing ks
  short8 wh[2][3], wl[2][3];
#pragma unroll
  for (int mat = 0; mat < 3; ++mat) {
    wh[0][mat] = *(const short8*)(WTh + wbase[mat]);
    wl[0][mat] = *(const short8*)(WTl + wbase[mat]);
  }

#pragma unroll
  for (int ks = 0; ks < 4; ++ks) {
    const int cur = ks & 1, nxt = cur ^ 1;
    if (ks < 3) {
#pragma unroll
      for (int mat = 0; mat < 3; ++mat) {
        wh[nxt][mat] = *(const short8*)(WTh + wbase[mat] + (ks + 1) * 32);
        wl[nxt][mat] = *(const short8*)(WTl + wbase[mat] + (ks + 1) * 32);
      }
    }
    short8 afh[4], afl[4];
#pragma unroll
    for (int mt = 0; mt < 4; ++mt) {
      int off = (mt * 16 + lane16) * XPAD + ks * 32 + quad * 8;
      afh[mt] = *(const short8*)&xh[off];
      afl[mt] = *(const short8*)&xl[off];
    }
#pragma unroll
    for (int mat = 0; mat < 3; ++mat) {
#pragma unroll
      for (int mt = 0; mt < 4; ++mt) {
        acc[mat][mt] = MFMA(afh[mt], wh[cur][mat], acc[mat][mt], 0, 0, 0);
        acc[mat][mt] = MFMA(afl[mt], wh[cur][mat], acc[mat][mt], 0, 0, 0);
        acc[mat][mt] = MFMA(afh[mt], wl[cur][mat], acc[mat][mt], 0, 0, 0);
      }
    }
  }

  // bias (lane16 = col within head)
  {
    int col = w * 16 + lane16;
    float bias[3] = {bq[col], bk[col], bv[col]};
#pragma unroll
    for (int mat = 0; mat < 3; ++mat)
#pragma unroll
      for (int mt = 0; mt < 4; ++mt)
#pragma unroll
        for (int r = 0; r < 4; ++r) acc[mat][mt][r] += bias[mat];
  }

  // rope + elu+1 on q (mat 0) and k (mat 1). lane16 = d; t = mt*16 + quad*4 + r.
  {
    const int d = lane16, j = d & 7;
#pragma unroll
    for (int mt = 0; mt < 4; ++mt) {
      float cc[4], ss[4];
#pragma unroll
      for (int r = 0; r < 4; ++r) {
        int tl = mt * 16 + quad * 4 + r;
        cc[r] = rc[tl][j]; ss[r] = rs[tl][j];
      }
#pragma unroll
      for (int mat = 0; mat < 2; ++mat) {
#pragma unroll
        for (int r = 0; r < 4; ++r) {
          float v = acc[mat][mt][r];
          float p = __shfl_xor(v, 8);          // pair (d, d+8)
          float nv = (d < 8) ? (v * cc[r] - p * ss[r]) : (p * ss[r] + v * cc[r]);
          acc[mat][mt][r] = (nv > 0.f) ? (nv + 1.f) : __expf(nv);
        }
      }
    }
  }

  // ksum[h=w][d] from k
  {
    float s = 0.f;
#pragma unroll
    for (int mt = 0; mt < 4; ++mt)
#pragma unroll
      for (int r = 0; r < 4; ++r) s += acc[1][mt][r];
    s += __shfl_xor(s, 16);
    s += __shfl_xor(s, 32);
    if (l < 16) atomicAdd(&ksum[(b * 8 + w) * 16 + lane16], s);
  }

  // q' -> ws bf16 [t][128]
#pragma unroll
  for (int mt = 0; mt < 4; ++mt)
#pragma unroll
    for (int r = 0; r < 4; ++r)
      qws[(size_t)(row0 + mt * 16 + quad * 4 + r) * 128 + w * 16 + lane16] =
          bfh(acc[0][mt][r]);

  // ctx[h=w] += K^T V via register transposes (2 t-windows of 32)
  {
    floatx4 c = (floatx4){0.f, 0.f, 0.f, 0.f};
#pragma unroll
    for (int ks2 = 0; ks2 < 2; ++ks2) {
      short8 kh, kl, vh, vl;
      xpose_frag(acc[1][ks2 * 2], acc[1][ks2 * 2 + 1], lane16, quad, kh, kl);
      xpose_frag(acc[2][ks2 * 2], acc[2][ks2 * 2 + 1], lane16, quad, vh, vl);
      c = MFMA(kh, vh, c, 0, 0, 0);
      c = MFMA(kl, vh, c, 0, 0, 0);
      c = MFMA(kh, vl, c, 0, 0, 0);
    }
#pragma unroll
    for (int r = 0; r < 4; ++r)
      atomicAdd(&ctx[((size_t)(b * 8 + w) * 16 + quad * 4 + r) * 16 + lane16], c[r]);
  }
}

// ---------------- k_mprep: M = C_h @ Wo_h (fp32) -> frag-major permuted split-bf16 ----------------
// Consumer frag (nt,ks), lane l reads 16B at group ((nt*4+ks)*64 + l); element j = qc ks*32+(l>>4)*8+j.
__global__ void k_mprep(const float* __restrict__ Wo, const float* __restrict__ ctx,
                        unsigned short* __restrict__ MTh, unsigned short* __restrict__ MTl) {
  int gid = blockIdx.x * 256 + threadIdx.x;   // 64 blocks: 8 b x 128 oc x 16 qc-groups
  int b = gid >> 11, r = gid & 2047, oc = r >> 4, qcg = r & 15;
  int h = qcg >> 1, d0 = (qcg & 1) * 8;
  const float* C = ctx + (size_t)(b * 8 + h) * 256;   // [d][e]
  float m[8] = {0.f, 0.f, 0.f, 0.f, 0.f, 0.f, 0.f, 0.f};
#pragma unroll 4
  for (int e = 0; e < 16; ++e) {
    float wv = Wo[(size_t)(h * 16 + e) * 128 + oc];
#pragma unroll
    for (int i = 0; i < 8; ++i) m[i] += C[(d0 + i) * 16 + e] * wv;
  }
  union { uint4 q; unsigned short u[8]; } oh, ol;
#pragma unroll
  for (int i = 0; i < 8; ++i) splitf(m[i], oh.u[i], ol.u[i]);
  // permuted group index: nt=oc>>4, ks=qcg>>2, l = (qcg&3)*16 + (oc&15)
  int grp = (((oc >> 4) * 4 + (qcg >> 2)) * 64) + (qcg & 3) * 16 + (oc & 15);
  *(uint4*)&MTh[(size_t)b * 16384 + grp * 8] = oh.q;
  *(uint4*)&MTl[(size_t)b * 16384 + grp * 8] = ol.q;
}

// ---------------- kernel 2: out = (z .* q') @ M + bo. M staged in LDS. ----------------
// 512 blocks x 512 thr (8 waves); block = 128 rows, wave w = one 16-row m-tile.
// Same 64KB LDS staging as R8 (2 blocks/CU), but 8 waves -> 4 waves/SIMD (was 2),
// per-wave state halved (oacc 32 regs, A-frags 16), staging prologue split 8 ways.
__global__ __launch_bounds__(512) void k_zout(
    const unsigned short* __restrict__ qws,
    const unsigned short* __restrict__ MTh, const unsigned short* __restrict__ MTl,
    const float* __restrict__ bo, const float* __restrict__ ksum,
    float* __restrict__ out) {
  __shared__ __align__(16) unsigned short mh[16384], ml[16384];  // 32KB + 32KB, frag-major
  __shared__ float ksumS[128], boS[128];
  const int tid = threadIdx.x;
  const int row0 = blockIdx.x * 128;
  const int b = row0 >> 13;
  const int l = tid & 63, w = tid >> 6;
  const int lane16 = l & 15, quad = l >> 4;

  {  // async-stage M (this batch's 64KB) into LDS: wave w copies chunks (i*8+w)*1KB
    const char* gh = (const char*)(MTh + (size_t)b * 16384);
    const char* gl = (const char*)(MTl + (size_t)b * 16384);
#pragma unroll
    for (int i = 0; i < 4; ++i) {
      int off = (i * 8 + w) * 1024 + l * 16;
      async16(gh + off, (char*)mh + off);
      async16(gl + off, (char*)ml + off);
    }
  }
  if (tid < 128) ksumS[tid] = ksum[b * 128 + tid];
  else if (tid < 256) boS[tid - 128] = bo[tid - 128];
  __syncthreads();                 // drains async staging too

  // A-frags: q' direct from ws (already frag-layout), z in-reg, scale+split
  short8 ah[4], al[4];
  {
    int trow = row0 + w * 16 + lane16;      // lane16 = t within the wave's 16-row strip
#pragma unroll
    for (int ks = 0; ks < 4; ++ks) {
      union { short8 s8; unsigned short u[8]; } qq;
      qq.s8 = *(const short8*)&qws[(size_t)trow * 128 + ks * 32 + quad * 8];
      int kb = ks * 32 + quad * 8;
      float s = 0.f;
#pragma unroll
      for (int j = 0; j < 8; ++j) s += bfdec(qq.u[j]) * ksumS[kb + j];
      s += __shfl_xor(s, 16);        // combine the two 8-halves of the head
      float z = 1.0f / (s + 1e-6f);
      union { short8 s8; unsigned short u[8]; } H, L;
#pragma unroll
      for (int j = 0; j < 8; ++j) splitf(bfdec(qq.u[j]) * z, H.u[j], L.u[j]);
      ah[ks] = H.s8;
      al[ks] = L.s8;
    }
  }

  floatx4 oacc[8];
#pragma unroll
  for (int i = 0; i < 8; ++i) oacc[i] = (floatx4){0.f, 0.f, 0.f, 0.f};

#pragma unroll
  for (int nt = 0; nt < 8; ++nt) {
#pragma unroll
    for (int ks = 0; ks < 4; ++ks) {
      int moff = ((nt * 4 + ks) * 64 + l) * 8;        // frag-major: lane-contiguous 16B
      short8 wbh = *(const short8*)&mh[moff];
      short8 wbl = *(const short8*)&ml[moff];
      oacc[nt] = MFMA(ah[ks], wbh, oacc[nt], 0, 0, 0);
      oacc[nt] = MFMA(al[ks], wbh, oacc[nt], 0, 0, 0);
      oacc[nt] = MFMA(ah[ks], wbl, oacc[nt], 0, 0, 0);
    }
  }

#pragma unroll
  for (int nt = 0; nt < 8; ++nt) {
    int oc = nt * 16 + lane16;
    float bb = boS[oc];
#pragma unroll
    for (int r = 0; r < 4; ++r) {
      int t = row0 + w * 16 + quad * 4 + r;
      out[(size_t)t * 128 + oc] = oacc[nt][r] + bb;
    }
  }
}

extern "C" void kernel_launch(void* const* d_in, const int* in_sizes, int n_in,
                              void* d_out, int out_size, void* d_ws, size_t ws_size,
                              hipStream_t stream) {
  const float* x  = (const float*)d_in[0];
  const float* Wq = (const float*)d_in[1];
  const float* bq = (const float*)d_in[2];
  const float* Wk = (const float*)d_in[3];
  const float* bk = (const float*)d_in[4];
  const float* Wv = (const float*)d_in[5];
  const float* bv = (const float*)d_in[6];
  const float* Wo = (const float*)d_in[7];
  const float* bo = (const float*)d_in[8];
  float* out = (float*)d_out;

  // ws: qws 16.78MB | WTh 96KB | WTl 96KB | ctx 64KB | ksum 4KB | MTh 256KB | MTl 256KB
  unsigned short* qws = (unsigned short*)d_ws;         // 65536*128 shorts
  unsigned short* WTh = qws + 8388608;                 // 3 x 16384
  unsigned short* WTl = WTh + 49152;
  float* ctx  = (float*)(WTl + 49152);                 // 16384 f
  float* ksum = ctx + 16384;                           // 1024 f
  unsigned short* MTh = (unsigned short*)(ksum + 1024);  // 8 x 16384
  unsigned short* MTl = MTh + 131072;

  k_prep<<<92, 256, 0, stream>>>(Wq, Wk, Wv, WTh, WTl, ctx);
  k_qkv<<<1024, 512, 0, stream>>>(x, WTh, WTl, bq, bk, bv, ctx, ksum, qws);
  k_mprep<<<64, 256, 0, stream>>>(Wo, ctx, MTh, MTl);
  k_zout<<<512, 512, 0, stream>>>(qws, MTh, MTl, bo, ksum, out);
}